// Round 4
// baseline (623.559 us; speedup 1.0000x reference)
//
#include <hip/hip_runtime.h>
#include <math.h>

typedef __bf16 bf16x8 __attribute__((ext_vector_type(8)));
typedef __bf16 bf16x4 __attribute__((ext_vector_type(4)));
typedef float  f32x4  __attribute__((ext_vector_type(4)));

#define NTOK 4096
#define CDIM 1024
#define EEXP 8
#define IDIM 2048

__device__ __forceinline__ void async_copy16(const __bf16* g, __bf16* l) {
  __builtin_amdgcn_global_load_lds((const __attribute__((address_space(1))) void*)g,
                                   (__attribute__((address_space(3))) void*)l,
                                   16, 0, 0);
}

// tanh-form gelu: max abs dev from exact erf-gelu ~3e-4
__device__ __forceinline__ float gelu_f(float x) {
  float u = 0.7978845608028654f * fmaf(0.044715f * x * x, x, x);
  float ex = __expf(-2.f * fabsf(u));
  float th = copysignf((1.f - ex) / (1.f + ex), u);
  return 0.5f * x * (1.f + th);
}

// ---------------- gating + compaction + h->bf16 (one block per token) ----------------
__global__ __launch_bounds__(256) void gating_kernel(
    const float* __restrict__ h, const float* __restrict__ sim,
    const float* __restrict__ gates, const float* __restrict__ temp,
    const float* __restrict__ emask, const int* __restrict__ minexp,
    float* __restrict__ out_logits, float* __restrict__ out_act,
    float* __restrict__ inv_num, int* __restrict__ counts,
    unsigned short* __restrict__ perm, __bf16* __restrict__ hb)
{
  const int t = blockIdx.x, tid = threadIdx.x;
  float4 hv4 = ((const float4*)(h + (size_t)t * CDIM))[tid];
  float hv[4] = {hv4.x, hv4.y, hv4.z, hv4.w};
  // write bf16 copy of h
  bf16x4 hb4 = {(__bf16)hv[0], (__bf16)hv[1], (__bf16)hv[2], (__bf16)hv[3]};
  ((bf16x4*)(hb + (size_t)t * CDIM))[tid] = hb4;

  float d[EEXP], nn[EEXP];
  #pragma unroll
  for (int e = 0; e < EEXP; ++e) { d[e] = 0.f; nn[e] = 0.f; }
  float ss = 0.f;
  #pragma unroll
  for (int j = 0; j < 4; ++j) {
    ss = fmaf(hv[j], hv[j], ss);
    const float* sr = sim + (size_t)(tid * 4 + j) * EEXP;  // one sim row = 8 f32
    float4 s0 = ((const float4*)sr)[0];
    float4 s1 = ((const float4*)sr)[1];
    float sv[8] = {s0.x, s0.y, s0.z, s0.w, s1.x, s1.y, s1.z, s1.w};
    #pragma unroll
    for (int e = 0; e < EEXP; ++e) {
      d[e]  = fmaf(hv[j], sv[e], d[e]);
      nn[e] = fmaf(sv[e], sv[e], nn[e]);
    }
  }
  #pragma unroll
  for (int off = 32; off > 0; off >>= 1) {
    ss += __shfl_down(ss, off);
    #pragma unroll
    for (int e = 0; e < EEXP; ++e) {
      d[e]  += __shfl_down(d[e], off);
      nn[e] += __shfl_down(nn[e], off);
    }
  }
  __shared__ float red[4][20];
  const int wv = tid >> 6;
  if ((tid & 63) == 0) {
    red[wv][0] = ss;
    #pragma unroll
    for (int e = 0; e < EEXP; ++e) { red[wv][1 + e] = d[e]; red[wv][9 + e] = nn[e]; }
  }
  __syncthreads();
  if (tid == 0) {
    float sst = red[0][0] + red[1][0] + red[2][0] + red[3][0];
    float inv_h = 1.f / fmaxf(sqrtf(sst), 1e-12f);
    float ls = 1.f / (1.f + expf(-temp[0]));
    float logit[EEXP], act[EEXP];
    float cnt = 0.f;
    #pragma unroll
    for (int e = 0; e < EEXP; ++e) {
      float dot = red[0][1 + e] + red[1][1 + e] + red[2][1 + e] + red[3][1 + e];
      float nne = red[0][9 + e] + red[1][9 + e] + red[2][9 + e] + red[3][9 + e];
      float inv_s = 1.f / fmaxf(sqrtf(nne), 1e-12f);
      logit[e] = dot * inv_h * inv_s * emask[e];
      float g = logit[e] - gates[e] * ls;   // relu(x)>0 <=> x>0
      act[e] = (g > 0.f) ? 1.f : 0.f;
      cnt += act[e];
    }
    if (cnt == 0.f) {  // fallback: top-min_experts by logits (ties -> lowest index)
      int k = minexp[0];
      if (k > EEXP) k = EEXP;
      bool used[EEXP];
      #pragma unroll
      for (int e = 0; e < EEXP; ++e) used[e] = false;
      for (int j = 0; j < k; ++j) {
        int best = -1; float bv = 0.f;
        for (int e = 0; e < EEXP; ++e)
          if (!used[e] && (best < 0 || logit[e] > bv)) { best = e; bv = logit[e]; }
        if (best >= 0) { used[best] = true; act[best] = 1.f; cnt += 1.f; }
      }
    }
    float num = fmaxf(cnt, 1.f);
    inv_num[t] = 1.f / num;
    #pragma unroll
    for (int e = 0; e < EEXP; ++e) {
      out_logits[(size_t)t * EEXP + e] = logit[e];
      out_act[(size_t)t * EEXP + e]   = act[e];
      if (act[e] > 0.f) {
        int pos = atomicAdd(&counts[e], 1);
        perm[e * NTOK + pos] = (unsigned short)t;
      }
    }
  }
}

// ---------------- fp32 64x64 tiled transpose+convert: out_bf16[c][r] = in_f32[r][c] ----------------
__global__ __launch_bounds__(256) void transpose_f32_bf16(
    const float* __restrict__ in0, __bf16* __restrict__ out0, int R, int Cc,
    long sIn, long sOut)
{
  const float* in = in0 + (size_t)blockIdx.z * sIn;
  __bf16* out = out0 + (size_t)blockIdx.z * sOut;
  __shared__ __align__(16) __bf16 tile[64][72];
  const int tid = threadIdx.x;
  const int c0 = blockIdx.x * 64, r0 = blockIdx.y * 64;
  #pragma unroll
  for (int p = 0; p < 2; ++p) {
    int lin = p * 256 + tid;
    int r = lin >> 3, c8 = (lin & 7) * 8;
    const float* src = in + (size_t)(r0 + r) * Cc + c0 + c8;
    float4 v0 = ((const float4*)src)[0];
    float4 v1 = ((const float4*)src)[1];
    bf16x8 v = {(__bf16)v0.x, (__bf16)v0.y, (__bf16)v0.z, (__bf16)v0.w,
                (__bf16)v1.x, (__bf16)v1.y, (__bf16)v1.z, (__bf16)v1.w};
    *(bf16x8*)&tile[r][c8] = v;
  }
  __syncthreads();
  #pragma unroll
  for (int p = 0; p < 2; ++p) {
    int lin = p * 256 + tid;
    int oc = lin >> 3, j8 = (lin & 7) * 8;
    bf16x8 o;
    #pragma unroll
    for (int jj = 0; jj < 8; ++jj) o[jj] = tile[j8 + jj][oc];
    *(bf16x8*)(out + (size_t)(c0 + oc) * R + r0 + j8) = o;
  }
}

// ---------------- packed-token bf16 GEMM (m97 structure + LDS XOR swizzle) ----------------
// MODE 0 (gemm1): A = hb gathered via perm[e]; epilogue gelu*inv_num -> bf16 inter_pk[e]
// MODE 1 (gemm2): A = inter_pk[e] packed rows; epilogue atomicAdd scatter to out f32 by token
template <int MODE, int NN, int KK>
__global__ __launch_bounds__(256, 2) void gemm_pk(
    const __bf16* __restrict__ A0, const __bf16* __restrict__ B0,
    const int* __restrict__ counts, const unsigned short* __restrict__ perm,
    const float* __restrict__ inv_num, void* __restrict__ Cout)
{
  const int e = blockIdx.z;
  const int Me = counts[e];
  const int m0 = blockIdx.y * 128;
  if (m0 >= Me) return;                       // block-uniform, before any barrier
  const int n0 = blockIdx.x * 128;
  const int tid = threadIdx.x;
  const int wave = tid >> 6, lane = tid & 63;
  const int wm = (wave >> 1) * 64, wn = (wave & 1) * 64;
  const int quad = lane >> 4, lrow = lane & 15;
  const int srow = lane >> 2;
  // XOR swizzle: lane's global k-chunk = (lane&3) ^ ((srow>>1)&3); read back at quad ^ ((lrow>>1)&3)
  const int skol = (((lane & 3) ^ ((lane >> 3) & 3)) * 8);
  const int xk = (quad ^ ((lrow >> 1) & 3)) * 8;

  __shared__ __align__(16) __bf16 As[128 * 32];
  __shared__ __align__(16) __bf16 Bs[128 * 32];
  __bf16* lA = As + wave * 1024;              // wave-uniform base; HW adds lane*16B
  __bf16* lB = Bs + wave * 1024;

  const unsigned short* pe = perm + e * NTOK;
  const int ra0 = m0 + wave * 32 + srow;
  const int ca0 = min(ra0, Me - 1), ca1 = min(ra0 + 16, Me - 1);
  const __bf16* Ab0;
  const __bf16* Ab1;
  if (MODE == 0) {
    Ab0 = A0 + (size_t)pe[ca0] * KK + skol;   // gathered token rows
    Ab1 = A0 + (size_t)pe[ca1] * KK + skol;
  } else {
    const __bf16* Abase = A0 + (size_t)e * NTOK * KK;
    Ab0 = Abase + (size_t)ca0 * KK + skol;
    Ab1 = Abase + (size_t)ca1 * KK + skol;
  }
  const __bf16* Bb = B0 + (size_t)e * (CDIM * IDIM)
                   + (size_t)(n0 + wave * 32 + srow) * KK + skol;

  f32x4 acc[4][4] = {};

  for (int k0 = 0; k0 < KK; k0 += 32) {
    async_copy16(Ab0 + k0, lA);
    async_copy16(Ab1 + k0, lA + 512);
    async_copy16(Bb + k0, lB);
    async_copy16(Bb + (size_t)16 * KK + k0, lB + 512);
    __syncthreads();
    bf16x8 af[4], bfr[4];
    #pragma unroll
    for (int mi = 0; mi < 4; ++mi)
      af[mi] = *(const bf16x8*)(As + (wm + mi * 16 + lrow) * 32 + xk);
    #pragma unroll
    for (int ni = 0; ni < 4; ++ni)
      bfr[ni] = *(const bf16x8*)(Bs + (wn + ni * 16 + lrow) * 32 + xk);
    #pragma unroll
    for (int mi = 0; mi < 4; ++mi)
      #pragma unroll
      for (int ni = 0; ni < 4; ++ni)
        acc[mi][ni] = __builtin_amdgcn_mfma_f32_16x16x32_bf16(af[mi], bfr[ni], acc[mi][ni], 0, 0, 0);
    __syncthreads();
  }

  if (MODE == 0) {
    __bf16* O = (__bf16*)Cout + (size_t)e * NTOK * NN;
    #pragma unroll
    for (int mi = 0; mi < 4; ++mi) {
      #pragma unroll
      for (int r = 0; r < 4; ++r) {
        const int row = m0 + wm + mi * 16 + quad * 4 + r;    // packed row, < 4096
        const float sv = inv_num[pe[min(row, Me - 1)]];
        #pragma unroll
        for (int ni = 0; ni < 4; ++ni) {
          const int col = n0 + wn + ni * 16 + lrow;
          O[(size_t)row * NN + col] = (__bf16)(gelu_f(acc[mi][ni][r]) * sv);
        }
      }
    }
  } else {
    float* O = (float*)Cout;
    #pragma unroll
    for (int mi = 0; mi < 4; ++mi) {
      #pragma unroll
      for (int r = 0; r < 4; ++r) {
        const int row = m0 + wm + mi * 16 + quad * 4 + r;
        if (row < Me) {
          const int tok = pe[row];
          #pragma unroll
          for (int ni = 0; ni < 4; ++ni) {
            const int col = n0 + wn + ni * 16 + lrow;
            atomicAdd(&O[(size_t)tok * NN + col], acc[mi][ni][r]);
          }
        }
      }
    }
  }
}

extern "C" void kernel_launch(void* const* d_in, const int* in_sizes, int n_in,
                              void* d_out, int out_size, void* d_ws, size_t ws_size,
                              hipStream_t stream) {
  (void)in_sizes; (void)n_in; (void)out_size; (void)ws_size;
  const float* h     = (const float*)d_in[0];
  const float* sim   = (const float*)d_in[1];
  const float* gates = (const float*)d_in[2];
  const float* temp  = (const float*)d_in[3];
  const float* emask = (const float*)d_in[4];
  const float* w1    = (const float*)d_in[5];
  const float* w2    = (const float*)d_in[6];
  const int*   minexp = (const int*)d_in[7];

  float* out_final  = (float*)d_out;                        // [4096][1024]
  float* out_logits = out_final + (size_t)NTOK * CDIM;      // [4096][8]
  float* out_act    = out_logits + (size_t)NTOK * EEXP;     // [4096][8]

  char* ws = (char*)d_ws;                                   // ~200.1 MB used (ws >= 209846528 proven r3)
  float*          inv_num  = (float*)(ws + 0);              // [4096] f32 (16KB)
  int*            counts   = (int*)(ws + 16384);            // [8] i32 (memset 0)
  unsigned short* perm     = (unsigned short*)(ws + 16448); // [8][4096] u16 (64KB)
  __bf16*         hb       = (__bf16*)(ws + 81984);         // [4096][1024] bf16 (8MB)
  __bf16*         w1T_all  = (__bf16*)(ws + 8470592);       // [E][2048][1024] bf16 (32MB)
  __bf16*         w2T_all  = (__bf16*)(ws + 42025024);      // [E][1024][2048] bf16 (32MB)
  __bf16*         inter_pk = (__bf16*)(ws + 75579456);      // [E][4096][2048] bf16 (128MB)

  const long sW = (long)CDIM * IDIM;

  hipMemsetAsync(counts, 0, EEXP * sizeof(int), stream);
  hipMemsetAsync(out_final, 0, (size_t)NTOK * CDIM * sizeof(float), stream);
  // w1[e]: [C][I] f32 -> w1T [I][C] bf16;  w2[e]: [I][C] f32 -> w2T [C][I] bf16
  transpose_f32_bf16<<<dim3(IDIM / 64, CDIM / 64, EEXP), 256, 0, stream>>>(
      w1, w1T_all, CDIM, IDIM, sW, sW);
  transpose_f32_bf16<<<dim3(CDIM / 64, IDIM / 64, EEXP), 256, 0, stream>>>(
      w2, w2T_all, IDIM, CDIM, sW, sW);
  gating_kernel<<<NTOK, 256, 0, stream>>>(h, sim, gates, temp, emask, minexp,
                                          out_logits, out_act, inv_num, counts, perm, hb);
  // gemm1 (packed): inter_pk[e][0..Me) = gelu(hb[perm] @ w1[e]) * inv_num[perm]
  gemm_pk<0, IDIM, CDIM><<<dim3(IDIM / 128, NTOK / 128, EEXP), 256, 0, stream>>>(
      hb, w1T_all, counts, perm, inv_num, (void*)inter_pk);
  // gemm2 (packed): out[perm] += inter_pk[e] @ w2[e]
  gemm_pk<1, CDIM, IDIM><<<dim3(CDIM / 128, NTOK / 128, EEXP), 256, 0, stream>>>(
      inter_pk, w2T_all, counts, perm, inv_num, (void*)out_final);
}

// Round 5
// 475.378 us; speedup vs baseline: 1.3117x; 1.3117x over previous
//
#include <hip/hip_runtime.h>
#include <math.h>

typedef __bf16 bf16x8 __attribute__((ext_vector_type(8)));
typedef __bf16 bf16x4 __attribute__((ext_vector_type(4)));
typedef float  f32x4  __attribute__((ext_vector_type(4)));

#define NTOK 4096
#define CDIM 1024
#define EEXP 8
#define IDIM 2048

__device__ __forceinline__ void async_copy16(const __bf16* g, __bf16* l) {
  __builtin_amdgcn_global_load_lds((const __attribute__((address_space(1))) void*)g,
                                   (__attribute__((address_space(3))) void*)l,
                                   16, 0, 0);
}

// tanh-form gelu: max abs dev from exact erf-gelu ~3e-4
__device__ __forceinline__ float gelu_f(float x) {
  float u = 0.7978845608028654f * fmaf(0.044715f * x * x, x, x);
  float ex = __expf(-2.f * fabsf(u));
  float th = copysignf((1.f - ex) / (1.f + ex), u);
  return 0.5f * x * (1.f + th);
}

// ---------------- gating + h->bf16 (one block per token; NO atomics) ----------------
__global__ __launch_bounds__(256) void gating_kernel(
    const float* __restrict__ h, const float* __restrict__ sim,
    const float* __restrict__ gates, const float* __restrict__ temp,
    const float* __restrict__ emask, const int* __restrict__ minexp,
    float* __restrict__ out_logits, float* __restrict__ out_act,
    float* __restrict__ inv_num, __bf16* __restrict__ hb)
{
  const int t = blockIdx.x, tid = threadIdx.x;
  float4 hv4 = ((const float4*)(h + (size_t)t * CDIM))[tid];
  float hv[4] = {hv4.x, hv4.y, hv4.z, hv4.w};
  bf16x4 hb4 = {(__bf16)hv[0], (__bf16)hv[1], (__bf16)hv[2], (__bf16)hv[3]};
  ((bf16x4*)(hb + (size_t)t * CDIM))[tid] = hb4;

  float d[EEXP], nn[EEXP];
  #pragma unroll
  for (int e = 0; e < EEXP; ++e) { d[e] = 0.f; nn[e] = 0.f; }
  float ss = 0.f;
  #pragma unroll
  for (int j = 0; j < 4; ++j) {
    ss = fmaf(hv[j], hv[j], ss);
    const float* sr = sim + (size_t)(tid * 4 + j) * EEXP;  // one sim row = 8 f32
    float4 s0 = ((const float4*)sr)[0];
    float4 s1 = ((const float4*)sr)[1];
    float sv[8] = {s0.x, s0.y, s0.z, s0.w, s1.x, s1.y, s1.z, s1.w};
    #pragma unroll
    for (int e = 0; e < EEXP; ++e) {
      d[e]  = fmaf(hv[j], sv[e], d[e]);
      nn[e] = fmaf(sv[e], sv[e], nn[e]);
    }
  }
  #pragma unroll
  for (int off = 32; off > 0; off >>= 1) {
    ss += __shfl_down(ss, off);
    #pragma unroll
    for (int e = 0; e < EEXP; ++e) {
      d[e]  += __shfl_down(d[e], off);
      nn[e] += __shfl_down(nn[e], off);
    }
  }
  __shared__ float red[4][20];
  const int wv = tid >> 6;
  if ((tid & 63) == 0) {
    red[wv][0] = ss;
    #pragma unroll
    for (int e = 0; e < EEXP; ++e) { red[wv][1 + e] = d[e]; red[wv][9 + e] = nn[e]; }
  }
  __syncthreads();
  if (tid == 0) {
    float sst = red[0][0] + red[1][0] + red[2][0] + red[3][0];
    float inv_h = 1.f / fmaxf(sqrtf(sst), 1e-12f);
    float ls = 1.f / (1.f + expf(-temp[0]));
    float logit[EEXP], act[EEXP];
    float cnt = 0.f;
    #pragma unroll
    for (int e = 0; e < EEXP; ++e) {
      float dot = red[0][1 + e] + red[1][1 + e] + red[2][1 + e] + red[3][1 + e];
      float nne = red[0][9 + e] + red[1][9 + e] + red[2][9 + e] + red[3][9 + e];
      float inv_s = 1.f / fmaxf(sqrtf(nne), 1e-12f);
      logit[e] = dot * inv_h * inv_s * emask[e];
      float g = logit[e] - gates[e] * ls;   // relu(x)>0 <=> x>0
      act[e] = (g > 0.f) ? 1.f : 0.f;
      cnt += act[e];
    }
    if (cnt == 0.f) {  // fallback: top-min_experts by logits (ties -> lowest index)
      int k = minexp[0];
      if (k > EEXP) k = EEXP;
      bool used[EEXP];
      #pragma unroll
      for (int e = 0; e < EEXP; ++e) used[e] = false;
      for (int j = 0; j < k; ++j) {
        int best = -1; float bv = 0.f;
        for (int e = 0; e < EEXP; ++e)
          if (!used[e] && (best < 0 || logit[e] > bv)) { best = e; bv = logit[e]; }
        if (best >= 0) { used[best] = true; act[best] = 1.f; cnt += 1.f; }
      }
    }
    float num = fmaxf(cnt, 1.f);
    inv_num[t] = 1.f / num;
    #pragma unroll
    for (int e = 0; e < EEXP; ++e) {
      out_logits[(size_t)t * EEXP + e] = logit[e];
      out_act[(size_t)t * EEXP + e]   = act[e];
    }
  }
}

// ---------------- pack: one wave per expert, ballot prefix scan (no atomics) ----------------
__global__ __launch_bounds__(64) void pack_kernel(
    const float* __restrict__ out_act, int* __restrict__ counts,
    unsigned short* __restrict__ perm)
{
  const int e = blockIdx.x;
  const int lane = threadIdx.x;
  const unsigned long long ltmask = (lane == 63) ? ~0ULL >> 1 : (1ULL << lane) - 1ULL;
  int base = 0;
  for (int i = 0; i < NTOK / 64; ++i) {
    int tok = i * 64 + lane;
    bool f = out_act[(size_t)tok * EEXP + e] > 0.f;
    unsigned long long m = __ballot(f);
    if (f) perm[e * NTOK + base + __popcll(m & ltmask)] = (unsigned short)tok;
    base += __popcll(m);
  }
  if (lane == 0) counts[e] = base;
}

// ---------------- fp32 64x64 tiled transpose+convert: out_bf16[c][r] = in_f32[r][c] ----------------
__global__ __launch_bounds__(256) void transpose_f32_bf16(
    const float* __restrict__ in0, __bf16* __restrict__ out0, int R, int Cc,
    long sIn, long sOut)
{
  const float* in = in0 + (size_t)blockIdx.z * sIn;
  __bf16* out = out0 + (size_t)blockIdx.z * sOut;
  __shared__ __align__(16) __bf16 tile[64][72];
  const int tid = threadIdx.x;
  const int c0 = blockIdx.x * 64, r0 = blockIdx.y * 64;
  #pragma unroll
  for (int p = 0; p < 2; ++p) {
    int lin = p * 256 + tid;
    int r = lin >> 3, c8 = (lin & 7) * 8;
    const float* src = in + (size_t)(r0 + r) * Cc + c0 + c8;
    float4 v0 = ((const float4*)src)[0];
    float4 v1 = ((const float4*)src)[1];
    bf16x8 v = {(__bf16)v0.x, (__bf16)v0.y, (__bf16)v0.z, (__bf16)v0.w,
                (__bf16)v1.x, (__bf16)v1.y, (__bf16)v1.z, (__bf16)v1.w};
    *(bf16x8*)&tile[r][c8] = v;
  }
  __syncthreads();
  #pragma unroll
  for (int p = 0; p < 2; ++p) {
    int lin = p * 256 + tid;
    int oc = lin >> 3, j8 = (lin & 7) * 8;
    bf16x8 o;
    #pragma unroll
    for (int jj = 0; jj < 8; ++jj) o[jj] = tile[j8 + jj][oc];
    *(bf16x8*)(out + (size_t)(c0 + oc) * R + r0 + j8) = o;
  }
}

// ---------------- packed-token bf16 GEMM (m97 structure + LDS XOR swizzle) ----------------
// MODE 0 (gemm1): A = hb gathered via perm[e]; epilogue gelu*inv_num -> bf16 inter_pk[e]
// MODE 1 (gemm2): A = inter_pk[e] packed rows; epilogue atomicAdd scatter to out f32 by token
template <int MODE, int NN, int KK>
__global__ __launch_bounds__(256, 2) void gemm_pk(
    const __bf16* __restrict__ A0, const __bf16* __restrict__ B0,
    const int* __restrict__ counts, const unsigned short* __restrict__ perm,
    const float* __restrict__ inv_num, void* __restrict__ Cout)
{
  const int e = blockIdx.z;
  const int Me = counts[e];
  const int m0 = blockIdx.y * 128;
  if (m0 >= Me) return;                       // block-uniform, before any barrier
  const int n0 = blockIdx.x * 128;
  const int tid = threadIdx.x;
  const int wave = tid >> 6, lane = tid & 63;
  const int wm = (wave >> 1) * 64, wn = (wave & 1) * 64;
  const int quad = lane >> 4, lrow = lane & 15;
  const int srow = lane >> 2;
  // XOR swizzle: lane's k-chunk = (lane&3)^((lane>>3)&3); read back at quad^((lrow>>1)&3)
  const int skol = (((lane & 3) ^ ((lane >> 3) & 3)) * 8);
  const int xk = (quad ^ ((lrow >> 1) & 3)) * 8;

  __shared__ __align__(16) __bf16 As[128 * 32];
  __shared__ __align__(16) __bf16 Bs[128 * 32];
  __bf16* lA = As + wave * 1024;              // wave-uniform base; HW adds lane*16B
  __bf16* lB = Bs + wave * 1024;

  const unsigned short* pe = perm + e * NTOK;
  const int ra0 = m0 + wave * 32 + srow;
  const int ca0 = min(ra0, Me - 1), ca1 = min(ra0 + 16, Me - 1);
  const __bf16* Ab0;
  const __bf16* Ab1;
  if (MODE == 0) {
    Ab0 = A0 + (size_t)pe[ca0] * KK + skol;   // gathered token rows
    Ab1 = A0 + (size_t)pe[ca1] * KK + skol;
  } else {
    const __bf16* Abase = A0 + (size_t)e * NTOK * KK;
    Ab0 = Abase + (size_t)ca0 * KK + skol;
    Ab1 = Abase + (size_t)ca1 * KK + skol;
  }
  const __bf16* Bb = B0 + (size_t)e * (CDIM * IDIM)
                   + (size_t)(n0 + wave * 32 + srow) * KK + skol;

  f32x4 acc[4][4] = {};

  for (int k0 = 0; k0 < KK; k0 += 32) {
    async_copy16(Ab0 + k0, lA);
    async_copy16(Ab1 + k0, lA + 512);
    async_copy16(Bb + k0, lB);
    async_copy16(Bb + (size_t)16 * KK + k0, lB + 512);
    __syncthreads();
    bf16x8 af[4], bfr[4];
    #pragma unroll
    for (int mi = 0; mi < 4; ++mi)
      af[mi] = *(const bf16x8*)(As + (wm + mi * 16 + lrow) * 32 + xk);
    #pragma unroll
    for (int ni = 0; ni < 4; ++ni)
      bfr[ni] = *(const bf16x8*)(Bs + (wn + ni * 16 + lrow) * 32 + xk);
    #pragma unroll
    for (int mi = 0; mi < 4; ++mi)
      #pragma unroll
      for (int ni = 0; ni < 4; ++ni)
        acc[mi][ni] = __builtin_amdgcn_mfma_f32_16x16x32_bf16(af[mi], bfr[ni], acc[mi][ni], 0, 0, 0);
    __syncthreads();
  }

  if (MODE == 0) {
    __bf16* O = (__bf16*)Cout + (size_t)e * NTOK * NN;
    #pragma unroll
    for (int mi = 0; mi < 4; ++mi) {
      #pragma unroll
      for (int r = 0; r < 4; ++r) {
        const int row = m0 + wm + mi * 16 + quad * 4 + r;    // packed row, < 4096
        const float sv = inv_num[pe[min(row, Me - 1)]];
        #pragma unroll
        for (int ni = 0; ni < 4; ++ni) {
          const int col = n0 + wn + ni * 16 + lrow;
          O[(size_t)row * NN + col] = (__bf16)(gelu_f(acc[mi][ni][r]) * sv);
        }
      }
    }
  } else {
    float* O = (float*)Cout;
    #pragma unroll
    for (int mi = 0; mi < 4; ++mi) {
      #pragma unroll
      for (int r = 0; r < 4; ++r) {
        const int row = m0 + wm + mi * 16 + quad * 4 + r;
        if (row < Me) {
          const int tok = pe[row];
          #pragma unroll
          for (int ni = 0; ni < 4; ++ni) {
            const int col = n0 + wn + ni * 16 + lrow;
            atomicAdd(&O[(size_t)tok * NN + col], acc[mi][ni][r]);
          }
        }
      }
    }
  }
}

extern "C" void kernel_launch(void* const* d_in, const int* in_sizes, int n_in,
                              void* d_out, int out_size, void* d_ws, size_t ws_size,
                              hipStream_t stream) {
  (void)in_sizes; (void)n_in; (void)out_size; (void)ws_size;
  const float* h     = (const float*)d_in[0];
  const float* sim   = (const float*)d_in[1];
  const float* gates = (const float*)d_in[2];
  const float* temp  = (const float*)d_in[3];
  const float* emask = (const float*)d_in[4];
  const float* w1    = (const float*)d_in[5];
  const float* w2    = (const float*)d_in[6];
  const int*   minexp = (const int*)d_in[7];

  float* out_final  = (float*)d_out;                        // [4096][1024]
  float* out_logits = out_final + (size_t)NTOK * CDIM;      // [4096][8]
  float* out_act    = out_logits + (size_t)NTOK * EEXP;     // [4096][8]

  char* ws = (char*)d_ws;                                   // ~200.1 MB used (ws >= 209846528 proven r3)
  float*          inv_num  = (float*)(ws + 0);              // [4096] f32 (16KB)
  int*            counts   = (int*)(ws + 16384);            // [8] i32
  unsigned short* perm     = (unsigned short*)(ws + 16448); // [8][4096] u16 (64KB)
  __bf16*         hb       = (__bf16*)(ws + 81984);         // [4096][1024] bf16 (8MB)
  __bf16*         w1T_all  = (__bf16*)(ws + 8470592);       // [E][2048][1024] bf16 (32MB)
  __bf16*         w2T_all  = (__bf16*)(ws + 42025024);      // [E][1024][2048] bf16 (32MB)
  __bf16*         inter_pk = (__bf16*)(ws + 75579456);      // [E][4096][2048] bf16 (128MB)

  const long sW = (long)CDIM * IDIM;

  hipMemsetAsync(out_final, 0, (size_t)NTOK * CDIM * sizeof(float), stream);
  // w1[e]: [C][I] f32 -> w1T [I][C] bf16;  w2[e]: [I][C] f32 -> w2T [C][I] bf16
  transpose_f32_bf16<<<dim3(IDIM / 64, CDIM / 64, EEXP), 256, 0, stream>>>(
      w1, w1T_all, CDIM, IDIM, sW, sW);
  transpose_f32_bf16<<<dim3(CDIM / 64, IDIM / 64, EEXP), 256, 0, stream>>>(
      w2, w2T_all, IDIM, CDIM, sW, sW);
  gating_kernel<<<NTOK, 256, 0, stream>>>(h, sim, gates, temp, emask, minexp,
                                          out_logits, out_act, inv_num, hb);
  pack_kernel<<<EEXP, 64, 0, stream>>>(out_act, counts, perm);
  // gemm1 (packed): inter_pk[e][0..Me) = gelu(hb[perm] @ w1[e]) * inv_num[perm]
  gemm_pk<0, IDIM, CDIM><<<dim3(IDIM / 128, NTOK / 128, EEXP), 256, 0, stream>>>(
      hb, w1T_all, counts, perm, inv_num, (void*)inter_pk);
  // gemm2 (packed): out[perm] += inter_pk[e] @ w2[e]
  gemm_pk<1, CDIM, IDIM><<<dim3(CDIM / 128, NTOK / 128, EEXP), 256, 0, stream>>>(
      inter_pk, w2T_all, counts, perm, inv_num, (void*)out_final);
}